// Round 14
// baseline (156.799 us; speedup 1.0000x reference)
//
#include <hip/hip_runtime.h>
#include <hip/hip_bf16.h>

#define L_SEQ 2048
#define DMODEL 1024
#define DIN 2048
#define DTR 64
#define NST 16
#define CCH 128         // number of chunks
#define CHL 16          // L_SEQ / CCH
#define PSKST (L_SEQ * 96)   // Psk z-stride

typedef unsigned short u16;
typedef __bf16 bf16x8 __attribute__((ext_vector_type(8)));
typedef float f32x4 __attribute__((ext_vector_type(4)));

__device__ inline u16 f2bf(float v) {
    __bf16 h = (__bf16)v;
    return __builtin_bit_cast(unsigned short, h);
}
__device__ inline float bf2f(u16 v) {
    __bf16 h = __builtin_bit_cast(__bf16, v);
    return (float)h;
}
__device__ inline float rcpf(float x) { return __builtin_amdgcn_rcpf(x); }
__device__ inline float swishf(float v) { return v * rcpf(1.f + __expf(-v)); }
__device__ inline float softplusf(float v) {
    return (v > 20.f) ? v : __logf(1.f + __expf(v));
}

// p[n] = v^(n+1), depth-4 multiply tree
__device__ inline void powers16(float v, float* p) {
    p[0] = v;
    p[1] = v * v;
    p[2] = p[1] * v;
    p[3] = p[1] * p[1];
    p[4] = p[3] * p[0];  p[5] = p[3] * p[1];  p[6] = p[3] * p[2];  p[7] = p[3] * p[3];
    p[8] = p[7] * p[0];  p[9] = p[7] * p[1];  p[10] = p[7] * p[2]; p[11] = p[7] * p[3];
    p[12] = p[7] * p[4]; p[13] = p[7] * p[5]; p[14] = p[7] * p[6]; p[15] = p[7] * p[7];
}

// ================= bf16 MFMA GEMM: C = A[M,K] * Bt[N,K]^T =================
// LDS K-chunk XOR swizzle + counted-vmcnt pipeline (never vmcnt(0) in loop).
// EPI: 0 = plain fp32 C[M][N]; 2 = split (xiraw bf16 / gate bf16)
template<int TBN, int EPI>
__global__ __launch_bounds__(256) void gemm_bf16(const u16* __restrict__ A,
                                                 const u16* __restrict__ Bt,
                                                 float* __restrict__ C,
                                                 u16* __restrict__ xiraw,
                                                 u16* __restrict__ gateb,
                                                 int M, int N, int K) {
    constexpr int LDSZ = (128 + TBN) * 64;
    constexpr int ROUNDS = (128 + TBN) / 32;
    constexpr int FN = TBN / 32;
    __shared__ u16 smem[2 * LDSZ];

    const int tid = threadIdx.x;
    const int lane = tid & 63;
    const int wid = tid >> 6;
    const int wm = wid >> 1;
    const int wn = wid & 1;
    const int bm = blockIdx.y * 128;
    const int bn = blockIdx.x * TBN;

    const int srow8 = lane >> 3;
    const int schunk = lane & 7;
    const int sgchunk = schunk ^ srow8;
    const int lm = lane & 15;
    const int lk = lane >> 4;

    f32x4 acc[4][FN];
#pragma unroll
    for (int i = 0; i < 4; ++i)
#pragma unroll
        for (int j = 0; j < FN; ++j) acc[i][j] = (f32x4){0.f, 0.f, 0.f, 0.f};

    auto stage = [&](int buf, int t) {
        const int k0 = t * 64;
        u16* base = smem + buf * LDSZ;
#pragma unroll
        for (int rr = 0; rr < ROUNDS; ++rr) {
            int row = rr * 32 + wid * 8;
            int grow = row + srow8;
            const u16* src;
            if (row < 128) src = A + (size_t)(bm + grow) * K + k0 + sgchunk * 8;
            else           src = Bt + (size_t)(bn + grow - 128) * K + k0 + sgchunk * 8;
            u16* dst = base + row * 64;
            __builtin_amdgcn_global_load_lds(
                (const __attribute__((address_space(1))) void*)src,
                (__attribute__((address_space(3))) void*)dst, 16, 0, 0);
        }
    };

    auto compute = [&](int buf) {
        const u16* base = smem + buf * LDSZ;
#pragma unroll
        for (int kk = 0; kk < 2; ++kk) {
            bf16x8 av[4], bv[FN];
#pragma unroll
            for (int fm = 0; fm < 4; ++fm) {
                int row = wm * 64 + fm * 16 + lm;
                int slot = (kk * 4 + lk) ^ (row & 7);
                av[fm] = *(const bf16x8*)(base + row * 64 + slot * 8);
            }
#pragma unroll
            for (int fn = 0; fn < FN; ++fn) {
                int row = 128 + wn * (TBN / 2) + fn * 16 + lm;
                int slot = (kk * 4 + lk) ^ (row & 7);
                bv[fn] = *(const bf16x8*)(base + row * 64 + slot * 8);
            }
#pragma unroll
            for (int fm = 0; fm < 4; ++fm)
#pragma unroll
                for (int fn = 0; fn < FN; ++fn)
                    acc[fm][fn] = __builtin_amdgcn_mfma_f32_16x16x32_bf16(av[fm], bv[fn], acc[fm][fn], 0, 0, 0);
        }
    };

    const int nt = K / 64;
    int cur = 0;
    stage(0, 0);
    for (int t = 0; t < nt - 1; ++t) {
        stage(cur ^ 1, t + 1);
        asm volatile("s_waitcnt vmcnt(%0) lgkmcnt(0)\n\ts_barrier"
                     :: "n"(ROUNDS) : "memory");
        compute(cur);
        asm volatile("s_waitcnt lgkmcnt(0)\n\ts_barrier" ::: "memory");
        cur ^= 1;
    }
    asm volatile("s_waitcnt vmcnt(0) lgkmcnt(0)\n\ts_barrier" ::: "memory");
    compute(cur);

#pragma unroll
    for (int fm = 0; fm < 4; ++fm) {
#pragma unroll
        for (int fn = 0; fn < FN; ++fn) {
            int col = bn + wn * (TBN / 2) + fn * 16 + lm;
#pragma unroll
            for (int j = 0; j < 4; ++j) {
                int row = bm + wm * 64 + fm * 16 + lk * 4 + j;
                float v = acc[fm][fn][j];
                if (EPI == 0) {
                    C[(size_t)row * N + col] = v;
                } else {
                    if (col < DIN) xiraw[(size_t)row * DIN + col] = f2bf(v);
                    else           gateb[(size_t)row * DIN + (col - DIN)] = f2bf(swishf(v));
                }
            }
        }
    }
}

// ======== thin bf16 MFMA split-K GEMM (xi @ W_x): BM=128, TBN=32 ========
__global__ __launch_bounds__(256) void gemm_bf16_sk(const u16* __restrict__ A, int lda,
                                                    const u16* __restrict__ Bt, int ldb,
                                                    float* __restrict__ P,
                                                    int M, int N, int K, int kc) {
    constexpr int TBN = 32;
    constexpr int LDSZ = (128 + TBN) * 64;
    constexpr int ROUNDS = (128 + TBN) / 32;
    __shared__ u16 smem[2 * LDSZ];

    const int tid = threadIdx.x;
    const int lane = tid & 63;
    const int wid = tid >> 6;
    const int wm = wid >> 1;
    const int wn = wid & 1;
    const int bm = blockIdx.y * 128;
    const int bn = blockIdx.x * TBN;
    const int kbeg = blockIdx.z * kc;
    float* Cz = P + (size_t)blockIdx.z * M * N;

    const int srow8 = lane >> 3;
    const int schunk = lane & 7;
    const int sgchunk = schunk ^ srow8;
    const int lm = lane & 15;
    const int lk = lane >> 4;

    f32x4 acc[4];
#pragma unroll
    for (int i = 0; i < 4; ++i) acc[i] = (f32x4){0.f, 0.f, 0.f, 0.f};

    auto stage = [&](int buf, int t) {
        const int k0 = kbeg + t * 64;
        u16* base = smem + buf * LDSZ;
#pragma unroll
        for (int rr = 0; rr < ROUNDS; ++rr) {
            int row = rr * 32 + wid * 8;
            int grow = row + srow8;
            const u16* src;
            if (row < 128) src = A + (size_t)(bm + grow) * lda + k0 + sgchunk * 8;
            else           src = Bt + (size_t)(bn + grow - 128) * ldb + k0 + sgchunk * 8;
            u16* dst = base + row * 64;
            __builtin_amdgcn_global_load_lds(
                (const __attribute__((address_space(1))) void*)src,
                (__attribute__((address_space(3))) void*)dst, 16, 0, 0);
        }
    };

    auto compute = [&](int buf) {
        const u16* base = smem + buf * LDSZ;
#pragma unroll
        for (int kk = 0; kk < 2; ++kk) {
            bf16x8 av[4], bv;
#pragma unroll
            for (int fm = 0; fm < 4; ++fm) {
                int row = wm * 64 + fm * 16 + lm;
                int slot = (kk * 4 + lk) ^ (row & 7);
                av[fm] = *(const bf16x8*)(base + row * 64 + slot * 8);
            }
            {
                int row = 128 + wn * 16 + lm;
                int slot = (kk * 4 + lk) ^ (row & 7);
                bv = *(const bf16x8*)(base + row * 64 + slot * 8);
            }
#pragma unroll
            for (int fm = 0; fm < 4; ++fm)
                acc[fm] = __builtin_amdgcn_mfma_f32_16x16x32_bf16(av[fm], bv, acc[fm], 0, 0, 0);
        }
    };

    const int nt = kc / 64;
    int cur = 0;
    stage(0, 0);
    for (int t = 0; t < nt - 1; ++t) {
        stage(cur ^ 1, t + 1);
        asm volatile("s_waitcnt vmcnt(%0) lgkmcnt(0)\n\ts_barrier"
                     :: "n"(ROUNDS) : "memory");
        compute(cur);
        asm volatile("s_waitcnt lgkmcnt(0)\n\ts_barrier" ::: "memory");
        cur ^= 1;
    }
    asm volatile("s_waitcnt vmcnt(0) lgkmcnt(0)\n\ts_barrier" ::: "memory");
    compute(cur);

#pragma unroll
    for (int fm = 0; fm < 4; ++fm) {
        int col = bn + wn * 16 + lm;
#pragma unroll
        for (int j = 0; j < 4; ++j) {
            int row = bm + wm * 64 + fm * 16 + lk * 4 + j;
            Cz[(size_t)row * N + col] = acc[fm][j];
        }
    }
}

// ======== delta GEMM, K=64 single tile, fused split-K A-reduce ========
// deltaT[N][M] = softplus((Σz Psk[z][:, 0:64]) @ WdtT^T + b)^T.  BM=128, TBN=64.
__global__ __launch_bounds__(256) void gemm_delta(const float* __restrict__ Psk,
                                                  const u16* __restrict__ WdtT,
                                                  float* __restrict__ deltaT,
                                                  const float* __restrict__ bias) {
    constexpr int TBN = 64;
    __shared__ u16 smem[(128 + TBN) * 64];   // 24 KB, single buffer
    const int tid = threadIdx.x;
    const int lane = tid & 63;
    const int wid = tid >> 6;
    const int wm = wid >> 1;
    const int wn = wid & 1;
    const int bm = blockIdx.y * 128;
    const int bn = blockIdx.x * TBN;
    const int srow8 = lane >> 3;
    const int schunk = lane & 7;
    const int sgchunk = schunk ^ srow8;
    const int lm = lane & 15;
    const int lk = lane >> 4;

    // stage B (WdtT rows bn..bn+63, K=64) -> LDS rows 128..191 via global_load_lds
#pragma unroll
    for (int rr = 0; rr < 2; ++rr) {
        int row = rr * 32 + wid * 8;              // 0..63 (B-local)
        int grow = row + srow8;
        const u16* src = WdtT + (size_t)(bn + grow) * 64 + sgchunk * 8;
        u16* dst = smem + (128 + row) * 64;
        __builtin_amdgcn_global_load_lds(
            (const __attribute__((address_space(1))) void*)src,
            (__attribute__((address_space(3))) void*)dst, 16, 0, 0);
    }
    // stage A (rows 0..127): 4-partial reduce + bf16 + swizzle-matched ds_write.
    // elem (r,k) -> smem[r*64 + ((k>>3)^(r&7))*8 + (k&7)]  (slot s holds chunk s^(r&7))
#pragma unroll
    for (int i = 0; i < 32; ++i) {
        int idx = tid + i * 256;                  // 0..8191
        int r = idx >> 6;
        int k = idx & 63;
        size_t off = (size_t)(bm + r) * 96 + k;
        float s = Psk[off] + Psk[off + PSKST] + Psk[off + 2 * PSKST] + Psk[off + 3 * PSKST];
        smem[r * 64 + (((k >> 3) ^ (r & 7)) << 3) + (k & 7)] = f2bf(s);
    }
    asm volatile("s_waitcnt vmcnt(0) lgkmcnt(0)\n\ts_barrier" ::: "memory");

    f32x4 acc[4][2];
#pragma unroll
    for (int i = 0; i < 4; ++i)
#pragma unroll
        for (int j = 0; j < 2; ++j) acc[i][j] = (f32x4){0.f, 0.f, 0.f, 0.f};
#pragma unroll
    for (int kk = 0; kk < 2; ++kk) {
        bf16x8 av[4], bv[2];
#pragma unroll
        for (int fm = 0; fm < 4; ++fm) {
            int row = wm * 64 + fm * 16 + lm;
            int slot = (kk * 4 + lk) ^ (row & 7);
            av[fm] = *(const bf16x8*)(smem + row * 64 + slot * 8);
        }
#pragma unroll
        for (int fn = 0; fn < 2; ++fn) {
            int row = 128 + wn * 32 + fn * 16 + lm;
            int slot = (kk * 4 + lk) ^ (row & 7);
            bv[fn] = *(const bf16x8*)(smem + row * 64 + slot * 8);
        }
#pragma unroll
        for (int fm = 0; fm < 4; ++fm)
#pragma unroll
            for (int fn = 0; fn < 2; ++fn)
                acc[fm][fn] = __builtin_amdgcn_mfma_f32_16x16x32_bf16(av[fm], bv[fn], acc[fm][fn], 0, 0, 0);
    }
    // transposed softplus epilogue: deltaT[col][rowb..rowb+3]
#pragma unroll
    for (int fm = 0; fm < 4; ++fm) {
#pragma unroll
        for (int fn = 0; fn < 2; ++fn) {
            int col = bn + wn * 32 + fn * 16 + lm;
            float b = bias[col];
            float4 o;
            o.x = softplusf(acc[fm][fn][0] + b);
            o.y = softplusf(acc[fm][fn][1] + b);
            o.z = softplusf(acc[fm][fn][2] + b);
            o.w = softplusf(acc[fm][fn][3] + b);
            int rowb = bm + wm * 64 + fm * 16 + lk * 4;
            *(float4*)(deltaT + (size_t)col * L_SEQ + rowb) = o;
        }
    }
}

// ================= fused input prep: x cast + 4 weight transpose-casts =================
__device__ inline void castT_dev(const float* __restrict__ W, u16* __restrict__ Wt,
                                 int K, int N, int bx, int by) {
    __shared__ u16 tile[64][65];
    int n0 = bx * 64, k0 = by * 64;
    int tn = threadIdx.x & 63, t4 = threadIdx.x >> 6;
#pragma unroll
    for (int j = 0; j < 16; ++j) {
        int k = t4 + j * 4;
        if (n0 + tn < N) tile[tn][k] = f2bf(W[(size_t)(k0 + k) * N + n0 + tn]);
    }
    __syncthreads();
#pragma unroll
    for (int j = 0; j < 16; ++j) {
        int n = t4 + j * 4;
        if (n0 + n < N) Wt[(size_t)(n0 + n) * K + k0 + tn] = tile[n][tn];
    }
}

__global__ __launch_bounds__(256) void prep_fused(const float* __restrict__ x,
                                                  const float* __restrict__ W_in,
                                                  const float* __restrict__ W_x,
                                                  const float* __restrict__ W_dt,
                                                  const float* __restrict__ W_out,
                                                  u16* __restrict__ xbf,
                                                  u16* __restrict__ WinT,
                                                  u16* __restrict__ WxT,
                                                  u16* __restrict__ WdtT,
                                                  u16* __restrict__ WoutT) {
    int b = blockIdx.x;
    if (b < 2048) {
        int i = b * 256 + threadIdx.x;
        float4 v = ((const float4*)x)[i];
        ushort4 o;
        o.x = f2bf(v.x); o.y = f2bf(v.y); o.z = f2bf(v.z); o.w = f2bf(v.w);
        ((ushort4*)xbf)[i] = o;
    } else if (b < 3072) {
        int t = b - 2048;
        castT_dev(W_in, WinT, DMODEL, 4096, t & 63, t >> 6);
    } else if (b < 3136) {
        int t = b - 3072;
        castT_dev(W_x, WxT, DIN, 96, t & 1, t >> 1);
    } else if (b < 3168) {
        int t = b - 3136;
        castT_dev(W_dt, WdtT, DTR, DIN, t, 0);
    } else {
        int t = b - 3168;
        castT_dev(W_out, WoutT, DIN, DMODEL, t & 15, t >> 4);
    }
}

// ====== causal depthwise conv(4) + bias + swish: bf16 in, bf16 out ======
__global__ __launch_bounds__(256) void conv_swish(const u16* __restrict__ xiraw,
                                                  const float* __restrict__ cw,
                                                  const float* __restrict__ cb,
                                                  u16* __restrict__ xib) {
    int id = blockIdx.x * 256 + threadIdx.x;
    int l = id >> 11;
    int d = id & (DIN - 1);
    float acc = cb[d];
#pragma unroll
    for (int k = 0; k < 4; ++k) {
        int ls = l - 3 + k;
        if (ls >= 0) acc += bf2f(xiraw[ls * DIN + d]) * cw[k * DIN + d];
    }
    xib[id] = f2bf(swishf(acc));
}

// ================= chunk-parallel selective scan, n-fused ========
// B,C staged from Psk partials (4-sum, same z-order as old reduce -> bitwise same).
__global__ __launch_bounds__(256) void scanA(const float* __restrict__ deltaT,
                                             const u16* __restrict__ u,
                                             const float* __restrict__ Psk,
                                             float* __restrict__ localQ,
                                             float* __restrict__ csum) {
    __shared__ float sh[CHL][16];
    const int tid = threadIdx.x;
    const int c = blockIdx.y;
    const int d = blockIdx.x * 256 + tid;
    const int l0 = c * CHL;
    {
        int l = tid >> 4, j = tid & 15;
        size_t off = (size_t)(l0 + l) * 96 + DTR + j;
        sh[l][j] = Psk[off] + Psk[off + PSKST] + Psk[off + 2 * PSKST] + Psk[off + 3 * PSKST];
    }
    __syncthreads();
    float dl[CHL];
    {
        const float4* dp = (const float4*)(deltaT + (size_t)d * L_SEQ + l0);
        float4 v0 = dp[0], v1 = dp[1], v2 = dp[2], v3 = dp[3];
        dl[0] = v0.x; dl[1] = v0.y; dl[2] = v0.z; dl[3] = v0.w;
        dl[4] = v1.x; dl[5] = v1.y; dl[6] = v1.z; dl[7] = v1.w;
        dl[8] = v2.x; dl[9] = v2.y; dl[10] = v2.z; dl[11] = v2.w;
        dl[12] = v3.x; dl[13] = v3.y; dl[14] = v3.z; dl[15] = v3.w;
    }
    u16 uls[CHL];
#pragma unroll
    for (int l = 0; l < CHL; ++l) uls[l] = u[(l0 + l) * DIN + d];

    float q[16];
#pragma unroll
    for (int n = 0; n < 16; ++n) q[n] = 0.f;
    float s = 0.f;
#pragma unroll 4
    for (int l = 0; l < CHL; ++l) {
        float dlv = dl[l];
        float ulv = bf2f(uls[l]);
        float bb[16];
        const float4* shv = (const float4*)&sh[l][0];
        *(float4*)&bb[0] = shv[0];  *(float4*)&bb[4] = shv[1];
        *(float4*)&bb[8] = shv[2];  *(float4*)&bb[12] = shv[3];
        float v = __expf(-dlv);
        float p[16];
        powers16(v, p);
        float dlul = dlv * ulv;
#pragma unroll
        for (int n = 0; n < 16; ++n) q[n] = q[n] * p[n] + dlul * bb[n];
        s += dlv;
    }
    float* dst = localQ + (size_t)(c * DIN + d) * 16;
    *(float4*)(dst + 0)  = make_float4(q[0], q[1], q[2], q[3]);
    *(float4*)(dst + 4)  = make_float4(q[4], q[5], q[6], q[7]);
    *(float4*)(dst + 8)  = make_float4(q[8], q[9], q[10], q[11]);
    *(float4*)(dst + 12) = make_float4(q[12], q[13], q[14], q[15]);
    csum[c * DIN + d] = s;
}

__global__ __launch_bounds__(256) void scanB(float* __restrict__ localQ,
                                             const float* __restrict__ csum,
                                             float* __restrict__ send) {
    int gid = blockIdx.x * 256 + threadIdx.x;
    int n = gid & 15;
    int d = gid >> 4;
    const float An = -(float)(n + 1);
    float q = 0.f;
#pragma unroll 4
    for (int c = 0; c < CCH; ++c) {
        float cs = csum[c * DIN + d];
        float w = __expf(An * cs);
        float* lq = localQ + (size_t)(c * DIN + d) * 16 + n;
        float lv = *lq;
        *lq = q;
        q = q * w + lv;
    }
    if (n == 0) {
        double ssum = 0.0;
        for (int c = CCH - 1; c >= 0; --c) {
            ssum += (double)csum[c * DIN + d];
            send[c * DIN + d] = (float)ssum;
        }
    }
}

__global__ __launch_bounds__(256) void scanC(const float* __restrict__ deltaT,
                                             const u16* __restrict__ u,
                                             const float* __restrict__ Psk,
                                             const float* __restrict__ localQ,
                                             const float* __restrict__ send,
                                             const float* __restrict__ Dvec,
                                             const u16* __restrict__ gateb,
                                             u16* __restrict__ ybf) {
    __shared__ float sh[CHL][32];
    const int tid = threadIdx.x;
    const int c = blockIdx.y;
    const int d = blockIdx.x * 256 + tid;
    const int l0 = c * CHL;
#pragma unroll
    for (int k = 0; k < 2; ++k) {
        int idx = tid + k * 256;
        int l = idx >> 5, j = idx & 31;
        size_t off = (size_t)(l0 + l) * 96 + DTR + j;
        sh[l][j] = Psk[off] + Psk[off + PSKST] + Psk[off + 2 * PSKST] + Psk[off + 3 * PSKST];
    }
    __syncthreads();
    float dl[CHL];
    {
        const float4* dp = (const float4*)(deltaT + (size_t)d * L_SEQ + l0);
        float4 v0 = dp[0], v1 = dp[1], v2 = dp[2], v3 = dp[3];
        dl[0] = v0.x; dl[1] = v0.y; dl[2] = v0.z; dl[3] = v0.w;
        dl[4] = v1.x; dl[5] = v1.y; dl[6] = v1.z; dl[7] = v1.w;
        dl[8] = v2.x; dl[9] = v2.y; dl[10] = v2.z; dl[11] = v2.w;
        dl[12] = v3.x; dl[13] = v3.y; dl[14] = v3.z; dl[15] = v3.w;
    }
    u16 uls[CHL];
#pragma unroll
    for (int l = 0; l < CHL; ++l) uls[l] = u[(l0 + l) * DIN + d];

    float q[16];
    {
        const float* src = localQ + (size_t)(c * DIN + d) * 16;
        float4 t0 = *(const float4*)(src + 0);
        float4 t1 = *(const float4*)(src + 4);
        float4 t2 = *(const float4*)(src + 8);
        float4 t3 = *(const float4*)(src + 12);
        q[0] = t0.x; q[1] = t0.y; q[2] = t0.z; q[3] = t0.w;
        q[4] = t1.x; q[5] = t1.y; q[6] = t1.z; q[7] = t1.w;
        q[8] = t2.x; q[9] = t2.y; q[10] = t2.z; q[11] = t2.w;
        q[12] = t3.x; q[13] = t3.y; q[14] = t3.z; q[15] = t3.w;
    }
    const float send_cd = send[c * DIN + d];
    const float Dd = Dvec[d];
    float s = 0.f;
#pragma unroll 4
    for (int l = 0; l < CHL; ++l) {
        float dlv = dl[l];
        float ulv = bf2f(uls[l]);
        float bb[32];
        const float4* shv = (const float4*)&sh[l][0];
        *(float4*)&bb[0]  = shv[0]; *(float4*)&bb[4]  = shv[1];
        *(float4*)&bb[8]  = shv[2]; *(float4*)&bb[12] = shv[3];
        *(float4*)&bb[16] = shv[4]; *(float4*)&bb[20] = shv[5];
        *(float4*)&bb[24] = shv[6]; *(float4*)&bb[28] = shv[7];
        float v = __expf(-dlv);
        float p[16];
        powers16(v, p);
        float dlul = dlv * ulv;
#pragma unroll
        for (int n = 0; n < 16; ++n) q[n] = q[n] * p[n] + dlul * bb[n];
        s += dlv;
        float suf = send_cd - s;
        float contrib;
        float ac[4] = {0.f, 0.f, 0.f, 0.f};
        if (suf < 0.8f) {                       // g ~= 1 (err < 4e-7)
#pragma unroll
            for (int n = 0; n < 16; ++n) ac[n & 3] += q[n] * bb[16 + n];
            contrib = (ac[0] + ac[1]) + (ac[2] + ac[3]);
        } else {
            float w = __expf(-suf);
            float e[16];
            powers16(w, e);
            if (suf > 40.f) {                   // el << eps: g = el*1e12
#pragma unroll
                for (int n = 0; n < 16; ++n) ac[n & 3] += (q[n] * e[n]) * bb[16 + n];
                contrib = ((ac[0] + ac[1]) + (ac[2] + ac[3])) * 1e12f;
            } else {                            // exact transition band
#pragma unroll
                for (int n = 0; n < 16; ++n) {
                    float g = e[n] * rcpf(e[n] + 1e-12f);
                    ac[n & 3] += (q[n] * g) * bb[16 + n];
                }
                contrib = (ac[0] + ac[1]) + (ac[2] + ac[3]);
            }
        }
        float y = contrib + ulv * Dd;
        float gv = bf2f(gateb[(l0 + l) * DIN + d]);
        ybf[(l0 + l) * DIN + d] = f2bf(y * gv);
    }
}

extern "C" void kernel_launch(void* const* d_in, const int* in_sizes, int n_in,
                              void* d_out, int out_size, void* d_ws, size_t ws_size,
                              hipStream_t stream) {
    const float* x      = (const float*)d_in[0];
    const float* W_in   = (const float*)d_in[1];
    const float* conv_w = (const float*)d_in[2];
    const float* conv_b = (const float*)d_in[3];
    const float* W_x    = (const float*)d_in[4];
    const float* W_dt   = (const float*)d_in[5];
    const float* b_dt   = (const float*)d_in[6];
    const float* Dvec   = (const float*)d_in[7];
    const float* W_out  = (const float*)d_in[8];
    float* out = (float*)d_out;

    // Layout (u16 buffers: N_u16 elements occupy N_u16/2 floats). < 256 MiB.
    float* ws = (float*)d_ws;
    u16*   xiraw  = (u16*)ws;               //  0        .. 2097152  (2048*2048 u16)
    u16*   gateb  = (u16*)(ws + 2097152);   //  2097152  .. 4194304  (2048*2048 u16)
    u16*   xibf   = (u16*)(ws + 4194304);   //  4194304  .. 6291456  (2048*2048 u16)
    float* deltaT = ws + 6291456;           //  6291456  .. 10485760 (4194304 f) [d][l]
    float* localQ = ws + 10485760;          // 10485760  .. 14680064 (4194304 f)
    float* csum   = ws + 14680064;          // 14680064  .. 14942208 (262144 f)
    float* send   = ws + 14942208;          // 14942208  .. 15204352 (262144 f)
    u16*   xbf    = (u16*)(ws + 15204352);  // 15204352  .. 16252928 (2048*1024 u16)
    u16*   WinT   = (u16*)(ws + 16252928);  // 16252928  .. 18350080 (4096*1024 u16)
    u16*   WxT    = (u16*)(ws + 18350080);  // 18350080  .. 18448384 (96*2048 u16)
    u16*   WdtT   = (u16*)(ws + 18448384);  // 18448384  .. 18513920 (2048*64 u16)
    u16*   WoutT  = (u16*)(ws + 18513920);  // 18513920  .. 19562496 (1024*2048 u16)
    float* Psk    = ws + 19562496;          // 19562496  .. 20348928 (786432 f, 4*2048*96)
    u16*   ybf    = (u16*)(ws + 20348928);  // 20348928  .. 22446080 (2048*2048 u16)

    // 1) fused prep: x->bf16 + all 4 weight transpose-casts
    prep_fused<<<3680, 256, 0, stream>>>(x, W_in, W_x, W_dt, W_out,
                                         xbf, WinT, WxT, WdtT, WoutT);
    // 2) x @ W_in -> split epilogue: xiraw (bf16) + gate = swish(res) (bf16)
    gemm_bf16<64, 2><<<dim3(4096 / 64, L_SEQ / 128), 256, 0, stream>>>(
        xbf, WinT, nullptr, xiraw, gateb, L_SEQ, 4096, DMODEL);
    // 3) xi = swish(causal_conv(xiraw)) -> bf16
    conv_swish<<<(L_SEQ * DIN) / 256, 256, 0, stream>>>(xiraw, conv_w, conv_b, xibf);
    // 4) Psk[z] = partial (xi @ W_x), split-K x4 (consumers do the reduce)
    gemm_bf16_sk<<<dim3(3, L_SEQ / 128, 4), 256, 0, stream>>>(
        xibf, DIN, WxT, DIN, Psk, L_SEQ, 96, DIN, 512);
    // 5) deltaT = softplus(reduce(Psk[:, :64]) @ W_dt + b_dt)^T  (fused A-reduce)
    gemm_delta<<<dim3(DIN / 64, L_SEQ / 128), 256, 0, stream>>>(
        Psk, WdtT, deltaT, b_dt);
    // 6) chunk-parallel scan (u = xibf bf16; B,C reduced from Psk in staging)
    scanA<<<dim3(DIN / 256, CCH), 256, 0, stream>>>(deltaT, xibf, Psk, localQ, csum);
    scanB<<<(DIN * NST) / 256, 256, 0, stream>>>(localQ, csum, send);
    scanC<<<dim3(DIN / 256, CCH), 256, 0, stream>>>(deltaT, xibf, Psk, localQ, send,
                                                    Dvec, gateb, ybf);
    // 7) out = ygated @ W_out
    gemm_bf16<32, 0><<<dim3(DMODEL / 32, L_SEQ / 128), 256, 0, stream>>>(
        ybf, WoutT, out, nullptr, nullptr, L_SEQ, DMODEL, DIN);
}

// Round 15
// 151.570 us; speedup vs baseline: 1.0345x; 1.0345x over previous
//
#include <hip/hip_runtime.h>
#include <hip/hip_bf16.h>

#define L_SEQ 2048
#define DMODEL 1024
#define DIN 2048
#define DTR 64
#define NST 16
#define CCH 128         // number of chunks
#define CHL 16          // L_SEQ / CCH

typedef unsigned short u16;
typedef __bf16 bf16x8 __attribute__((ext_vector_type(8)));
typedef float f32x4 __attribute__((ext_vector_type(4)));

__device__ inline u16 f2bf(float v) {
    __bf16 h = (__bf16)v;
    return __builtin_bit_cast(unsigned short, h);
}
__device__ inline float bf2f(u16 v) {
    __bf16 h = __builtin_bit_cast(__bf16, v);
    return (float)h;
}
__device__ inline float rcpf(float x) { return __builtin_amdgcn_rcpf(x); }
__device__ inline float swishf(float v) { return v * rcpf(1.f + __expf(-v)); }
__device__ inline float softplusf(float v) {
    return (v > 20.f) ? v : __logf(1.f + __expf(v));
}

// p[n] = v^(n+1), depth-4 multiply tree
__device__ inline void powers16(float v, float* p) {
    p[0] = v;
    p[1] = v * v;
    p[2] = p[1] * v;
    p[3] = p[1] * p[1];
    p[4] = p[3] * p[0];  p[5] = p[3] * p[1];  p[6] = p[3] * p[2];  p[7] = p[3] * p[3];
    p[8] = p[7] * p[0];  p[9] = p[7] * p[1];  p[10] = p[7] * p[2]; p[11] = p[7] * p[3];
    p[12] = p[7] * p[4]; p[13] = p[7] * p[5]; p[14] = p[7] * p[6]; p[15] = p[7] * p[7];
}

// ================= bf16 MFMA GEMM: C = A[M,K] * Bt[N,K]^T =================
// LDS K-chunk XOR swizzle + counted-vmcnt pipeline (never vmcnt(0) in loop).
// EPI: 0 = plain fp32 C; 1 = softplus(bias+v) fp32 C; 2 = split (xiraw bf16 / gate fp32)
template<int TBN, int EPI>
__global__ __launch_bounds__(256) void gemm_bf16(const u16* __restrict__ A,
                                                 const u16* __restrict__ Bt,
                                                 float* __restrict__ C,
                                                 const float* __restrict__ bias,
                                                 u16* __restrict__ xiraw,
                                                 float* __restrict__ gate,
                                                 int M, int N, int K) {
    constexpr int LDSZ = (128 + TBN) * 64;
    constexpr int ROUNDS = (128 + TBN) / 32;
    constexpr int FN = TBN / 32;
    __shared__ u16 smem[2 * LDSZ];

    const int tid = threadIdx.x;
    const int lane = tid & 63;
    const int wid = tid >> 6;
    const int wm = wid >> 1;
    const int wn = wid & 1;
    const int bm = blockIdx.y * 128;
    const int bn = blockIdx.x * TBN;

    const int srow8 = lane >> 3;
    const int schunk = lane & 7;
    const int sgchunk = schunk ^ srow8;
    const int lm = lane & 15;
    const int lk = lane >> 4;

    f32x4 acc[4][FN];
#pragma unroll
    for (int i = 0; i < 4; ++i)
#pragma unroll
        for (int j = 0; j < FN; ++j) acc[i][j] = (f32x4){0.f, 0.f, 0.f, 0.f};

    auto stage = [&](int buf, int t) {
        const int k0 = t * 64;
        u16* base = smem + buf * LDSZ;
#pragma unroll
        for (int rr = 0; rr < ROUNDS; ++rr) {
            int row = rr * 32 + wid * 8;
            int grow = row + srow8;
            const u16* src;
            if (row < 128) src = A + (size_t)(bm + grow) * K + k0 + sgchunk * 8;
            else           src = Bt + (size_t)(bn + grow - 128) * K + k0 + sgchunk * 8;
            u16* dst = base + row * 64;
            __builtin_amdgcn_global_load_lds(
                (const __attribute__((address_space(1))) void*)src,
                (__attribute__((address_space(3))) void*)dst, 16, 0, 0);
        }
    };

    auto compute = [&](int buf) {
        const u16* base = smem + buf * LDSZ;
#pragma unroll
        for (int kk = 0; kk < 2; ++kk) {
            bf16x8 av[4], bv[FN];
#pragma unroll
            for (int fm = 0; fm < 4; ++fm) {
                int row = wm * 64 + fm * 16 + lm;
                int slot = (kk * 4 + lk) ^ (row & 7);
                av[fm] = *(const bf16x8*)(base + row * 64 + slot * 8);
            }
#pragma unroll
            for (int fn = 0; fn < FN; ++fn) {
                int row = 128 + wn * (TBN / 2) + fn * 16 + lm;
                int slot = (kk * 4 + lk) ^ (row & 7);
                bv[fn] = *(const bf16x8*)(base + row * 64 + slot * 8);
            }
#pragma unroll
            for (int fm = 0; fm < 4; ++fm)
#pragma unroll
                for (int fn = 0; fn < FN; ++fn)
                    acc[fm][fn] = __builtin_amdgcn_mfma_f32_16x16x32_bf16(av[fm], bv[fn], acc[fm][fn], 0, 0, 0);
        }
    };

    const int nt = K / 64;
    int cur = 0;
    stage(0, 0);
    for (int t = 0; t < nt - 1; ++t) {
        stage(cur ^ 1, t + 1);
        asm volatile("s_waitcnt vmcnt(%0) lgkmcnt(0)\n\ts_barrier"
                     :: "n"(ROUNDS) : "memory");
        compute(cur);
        asm volatile("s_waitcnt lgkmcnt(0)\n\ts_barrier" ::: "memory");
        cur ^= 1;
    }
    asm volatile("s_waitcnt vmcnt(0) lgkmcnt(0)\n\ts_barrier" ::: "memory");
    compute(cur);

#pragma unroll
    for (int fm = 0; fm < 4; ++fm) {
#pragma unroll
        for (int fn = 0; fn < FN; ++fn) {
            int col = bn + wn * (TBN / 2) + fn * 16 + lm;
#pragma unroll
            for (int j = 0; j < 4; ++j) {
                int row = bm + wm * 64 + fm * 16 + lk * 4 + j;
                float v = acc[fm][fn][j];
                if (EPI == 0) {
                    C[(size_t)row * N + col] = v;
                } else if (EPI == 1) {
                    v += bias[col];
                    C[(size_t)row * N + col] = softplusf(v);
                } else {
                    if (col < DIN) xiraw[(size_t)row * DIN + col] = f2bf(v);
                    else           gate[(size_t)row * DIN + (col - DIN)] = swishf(v);
                }
            }
        }
    }
}

// ======== thin bf16 MFMA split-K GEMM (xi @ W_x): BM=128, TBN=32 ========
__global__ __launch_bounds__(256) void gemm_bf16_sk(const u16* __restrict__ A, int lda,
                                                    const u16* __restrict__ Bt, int ldb,
                                                    float* __restrict__ P,
                                                    int M, int N, int K, int kc) {
    constexpr int TBN = 32;
    constexpr int LDSZ = (128 + TBN) * 64;
    constexpr int ROUNDS = (128 + TBN) / 32;
    __shared__ u16 smem[2 * LDSZ];

    const int tid = threadIdx.x;
    const int lane = tid & 63;
    const int wid = tid >> 6;
    const int wm = wid >> 1;
    const int wn = wid & 1;
    const int bm = blockIdx.y * 128;
    const int bn = blockIdx.x * TBN;
    const int kbeg = blockIdx.z * kc;
    float* Cz = P + (size_t)blockIdx.z * M * N;

    const int srow8 = lane >> 3;
    const int schunk = lane & 7;
    const int sgchunk = schunk ^ srow8;
    const int lm = lane & 15;
    const int lk = lane >> 4;

    f32x4 acc[4];
#pragma unroll
    for (int i = 0; i < 4; ++i) acc[i] = (f32x4){0.f, 0.f, 0.f, 0.f};

    auto stage = [&](int buf, int t) {
        const int k0 = kbeg + t * 64;
        u16* base = smem + buf * LDSZ;
#pragma unroll
        for (int rr = 0; rr < ROUNDS; ++rr) {
            int row = rr * 32 + wid * 8;
            int grow = row + srow8;
            const u16* src;
            if (row < 128) src = A + (size_t)(bm + grow) * lda + k0 + sgchunk * 8;
            else           src = Bt + (size_t)(bn + grow - 128) * ldb + k0 + sgchunk * 8;
            u16* dst = base + row * 64;
            __builtin_amdgcn_global_load_lds(
                (const __attribute__((address_space(1))) void*)src,
                (__attribute__((address_space(3))) void*)dst, 16, 0, 0);
        }
    };

    auto compute = [&](int buf) {
        const u16* base = smem + buf * LDSZ;
#pragma unroll
        for (int kk = 0; kk < 2; ++kk) {
            bf16x8 av[4], bv;
#pragma unroll
            for (int fm = 0; fm < 4; ++fm) {
                int row = wm * 64 + fm * 16 + lm;
                int slot = (kk * 4 + lk) ^ (row & 7);
                av[fm] = *(const bf16x8*)(base + row * 64 + slot * 8);
            }
            {
                int row = 128 + wn * 16 + lm;
                int slot = (kk * 4 + lk) ^ (row & 7);
                bv = *(const bf16x8*)(base + row * 64 + slot * 8);
            }
#pragma unroll
            for (int fm = 0; fm < 4; ++fm)
                acc[fm] = __builtin_amdgcn_mfma_f32_16x16x32_bf16(av[fm], bv, acc[fm], 0, 0, 0);
        }
    };

    const int nt = kc / 64;
    int cur = 0;
    stage(0, 0);
    for (int t = 0; t < nt - 1; ++t) {
        stage(cur ^ 1, t + 1);
        asm volatile("s_waitcnt vmcnt(%0) lgkmcnt(0)\n\ts_barrier"
                     :: "n"(ROUNDS) : "memory");
        compute(cur);
        asm volatile("s_waitcnt lgkmcnt(0)\n\ts_barrier" ::: "memory");
        cur ^= 1;
    }
    asm volatile("s_waitcnt vmcnt(0) lgkmcnt(0)\n\ts_barrier" ::: "memory");
    compute(cur);

#pragma unroll
    for (int fm = 0; fm < 4; ++fm) {
        int col = bn + wn * 16 + lm;
#pragma unroll
        for (int j = 0; j < 4; ++j) {
            int row = bm + wm * 64 + fm * 16 + lk * 4 + j;
            Cz[(size_t)row * N + col] = acc[fm][j];
        }
    }
}

// ================= fused input prep: x cast + 4 weight transpose-casts =================
__device__ inline void castT_dev(const float* __restrict__ W, u16* __restrict__ Wt,
                                 int K, int N, int bx, int by) {
    __shared__ u16 tile[64][65];
    int n0 = bx * 64, k0 = by * 64;
    int tn = threadIdx.x & 63, t4 = threadIdx.x >> 6;
#pragma unroll
    for (int j = 0; j < 16; ++j) {
        int k = t4 + j * 4;
        if (n0 + tn < N) tile[tn][k] = f2bf(W[(size_t)(k0 + k) * N + n0 + tn]);
    }
    __syncthreads();
#pragma unroll
    for (int j = 0; j < 16; ++j) {
        int n = t4 + j * 4;
        if (n0 + n < N) Wt[(size_t)(n0 + n) * K + k0 + tn] = tile[n][tn];
    }
}

__global__ __launch_bounds__(256) void prep_fused(const float* __restrict__ x,
                                                  const float* __restrict__ W_in,
                                                  const float* __restrict__ W_x,
                                                  const float* __restrict__ W_dt,
                                                  const float* __restrict__ W_out,
                                                  u16* __restrict__ xbf,
                                                  u16* __restrict__ WinT,
                                                  u16* __restrict__ WxT,
                                                  u16* __restrict__ WdtT,
                                                  u16* __restrict__ WoutT) {
    int b = blockIdx.x;
    if (b < 2048) {
        int i = b * 256 + threadIdx.x;
        float4 v = ((const float4*)x)[i];
        ushort4 o;
        o.x = f2bf(v.x); o.y = f2bf(v.y); o.z = f2bf(v.z); o.w = f2bf(v.w);
        ((ushort4*)xbf)[i] = o;
    } else if (b < 3072) {
        int t = b - 2048;
        castT_dev(W_in, WinT, DMODEL, 4096, t & 63, t >> 6);
    } else if (b < 3136) {
        int t = b - 3072;
        castT_dev(W_x, WxT, DIN, 96, t & 1, t >> 1);
    } else if (b < 3168) {
        int t = b - 3136;
        castT_dev(W_dt, WdtT, DTR, DIN, t, 0);
    } else {
        int t = b - 3168;
        castT_dev(W_out, WoutT, DIN, DMODEL, t & 15, t >> 4);
    }
}

// ======== split-K reduce (4 partials) + fused bf16 cast of delta-rank cols ========
__global__ __launch_bounds__(256) void reduce_sk(const float* __restrict__ P,
                                                 float* __restrict__ xdbl,
                                                 u16* __restrict__ xdbf) {
    int i = blockIdx.x * 256 + threadIdx.x;   // < 2048*96
    float s = 0.f;
#pragma unroll
    for (int z = 0; z < 4; ++z) s += P[z * (L_SEQ * 96) + i];
    xdbl[i] = s;
    int l = i / 96, k = i - l * 96;
    if (k < DTR) xdbf[l * DTR + k] = f2bf(s);
}

// ====== causal depthwise conv(4) + bias + swish: bf16 in, bf16 out ======
__global__ __launch_bounds__(256) void conv_swish(const u16* __restrict__ xiraw,
                                                  const float* __restrict__ cw,
                                                  const float* __restrict__ cb,
                                                  u16* __restrict__ xib) {
    int id = blockIdx.x * 256 + threadIdx.x;
    int l = id >> 11;
    int d = id & (DIN - 1);
    float acc = cb[d];
#pragma unroll
    for (int k = 0; k < 4; ++k) {
        int ls = l - 3 + k;
        if (ls >= 0) acc += bf2f(xiraw[ls * DIN + d]) * cw[k * DIN + d];
    }
    xib[id] = f2bf(swishf(acc));
}

// ================= chunk-parallel selective scan, n-fused (u is bf16) ========
__global__ __launch_bounds__(256) void scanA(const float* __restrict__ delta,
                                             const u16* __restrict__ u,
                                             const float* __restrict__ xdbl,
                                             float* __restrict__ localQ,
                                             float* __restrict__ csum) {
    __shared__ float sh[CHL][16];
    const int tid = threadIdx.x;
    const int c = blockIdx.y;
    const int d = blockIdx.x * 256 + tid;
    const int l0 = c * CHL;
    {
        int l = tid >> 4, j = tid & 15;
        sh[l][j] = xdbl[(l0 + l) * 96 + DTR + j];
    }
    __syncthreads();
    float q[16];
#pragma unroll
    for (int n = 0; n < 16; ++n) q[n] = 0.f;
    float s = 0.f;
#pragma unroll 2
    for (int l = 0; l < CHL; ++l) {
        float dl = delta[(l0 + l) * DIN + d];
        float ul = bf2f(u[(l0 + l) * DIN + d]);
        float bb[16];
        const float4* shv = (const float4*)&sh[l][0];
        *(float4*)&bb[0] = shv[0];  *(float4*)&bb[4] = shv[1];
        *(float4*)&bb[8] = shv[2];  *(float4*)&bb[12] = shv[3];
        float v = __expf(-dl);
        float p[16];
        powers16(v, p);
        float dlul = dl * ul;
#pragma unroll
        for (int n = 0; n < 16; ++n) q[n] = q[n] * p[n] + dlul * bb[n];
        s += dl;
    }
    float* dst = localQ + (size_t)(c * DIN + d) * 16;
    *(float4*)(dst + 0)  = make_float4(q[0], q[1], q[2], q[3]);
    *(float4*)(dst + 4)  = make_float4(q[4], q[5], q[6], q[7]);
    *(float4*)(dst + 8)  = make_float4(q[8], q[9], q[10], q[11]);
    *(float4*)(dst + 12) = make_float4(q[12], q[13], q[14], q[15]);
    csum[c * DIN + d] = s;
}

__global__ __launch_bounds__(256) void scanB(float* __restrict__ localQ,
                                             const float* __restrict__ csum,
                                             float* __restrict__ send) {
    int gid = blockIdx.x * 256 + threadIdx.x;
    int n = gid & 15;
    int d = gid >> 4;
    const float An = -(float)(n + 1);
    float q = 0.f;
#pragma unroll 4
    for (int c = 0; c < CCH; ++c) {
        float cs = csum[c * DIN + d];
        float w = __expf(An * cs);
        float* lq = localQ + (size_t)(c * DIN + d) * 16 + n;
        float lv = *lq;
        *lq = q;
        q = q * w + lv;
    }
    if (n == 0) {
        double ssum = 0.0;
        for (int c = CCH - 1; c >= 0; --c) {
            ssum += (double)csum[c * DIN + d];
            send[c * DIN + d] = (float)ssum;
        }
    }
}

__global__ __launch_bounds__(256) void scanC(const float* __restrict__ delta,
                                             const u16* __restrict__ u,
                                             const float* __restrict__ xdbl,
                                             const float* __restrict__ localQ,
                                             const float* __restrict__ send,
                                             const float* __restrict__ Dvec,
                                             const float* __restrict__ gate,
                                             u16* __restrict__ ybf) {
    __shared__ float sh[CHL][32];
    const int tid = threadIdx.x;
    const int c = blockIdx.y;
    const int d = blockIdx.x * 256 + tid;
    const int l0 = c * CHL;
#pragma unroll
    for (int k = 0; k < 2; ++k) {
        int idx = tid + k * 256;
        int l = idx >> 5, j = idx & 31;
        sh[l][j] = xdbl[(l0 + l) * 96 + DTR + j];
    }
    __syncthreads();
    float q[16];
    {
        const float* src = localQ + (size_t)(c * DIN + d) * 16;
        float4 t0 = *(const float4*)(src + 0);
        float4 t1 = *(const float4*)(src + 4);
        float4 t2 = *(const float4*)(src + 8);
        float4 t3 = *(const float4*)(src + 12);
        q[0] = t0.x; q[1] = t0.y; q[2] = t0.z; q[3] = t0.w;
        q[4] = t1.x; q[5] = t1.y; q[6] = t1.z; q[7] = t1.w;
        q[8] = t2.x; q[9] = t2.y; q[10] = t2.z; q[11] = t2.w;
        q[12] = t3.x; q[13] = t3.y; q[14] = t3.z; q[15] = t3.w;
    }
    const float send_cd = send[c * DIN + d];
    const float Dd = Dvec[d];
    float s = 0.f;
#pragma unroll 2
    for (int l = 0; l < CHL; ++l) {
        float dl = delta[(l0 + l) * DIN + d];
        float ul = bf2f(u[(l0 + l) * DIN + d]);
        float bb[32];
        const float4* shv = (const float4*)&sh[l][0];
        *(float4*)&bb[0]  = shv[0]; *(float4*)&bb[4]  = shv[1];
        *(float4*)&bb[8]  = shv[2]; *(float4*)&bb[12] = shv[3];
        *(float4*)&bb[16] = shv[4]; *(float4*)&bb[20] = shv[5];
        *(float4*)&bb[24] = shv[6]; *(float4*)&bb[28] = shv[7];
        float v = __expf(-dl);
        float p[16];
        powers16(v, p);
        float dlul = dl * ul;
#pragma unroll
        for (int n = 0; n < 16; ++n) q[n] = q[n] * p[n] + dlul * bb[n];
        s += dl;
        float suf = send_cd - s;
        float contrib;
        float ac[4] = {0.f, 0.f, 0.f, 0.f};
        if (suf < 0.8f) {                       // g ~= 1 (err < 4e-7)
#pragma unroll
            for (int n = 0; n < 16; ++n) ac[n & 3] += q[n] * bb[16 + n];
            contrib = (ac[0] + ac[1]) + (ac[2] + ac[3]);
        } else {
            float w = __expf(-suf);
            float e[16];
            powers16(w, e);
            if (suf > 40.f) {                   // el << eps: g = el*1e12
#pragma unroll
                for (int n = 0; n < 16; ++n) ac[n & 3] += (q[n] * e[n]) * bb[16 + n];
                contrib = ((ac[0] + ac[1]) + (ac[2] + ac[3])) * 1e12f;
            } else {                            // exact transition band
#pragma unroll
                for (int n = 0; n < 16; ++n) {
                    float g = e[n] * rcpf(e[n] + 1e-12f);
                    ac[n & 3] += (q[n] * g) * bb[16 + n];
                }
                contrib = (ac[0] + ac[1]) + (ac[2] + ac[3]);
            }
        }
        float y = contrib + ul * Dd;
        ybf[(l0 + l) * DIN + d] = f2bf(y * gate[(l0 + l) * DIN + d]);
    }
}

extern "C" void kernel_launch(void* const* d_in, const int* in_sizes, int n_in,
                              void* d_out, int out_size, void* d_ws, size_t ws_size,
                              hipStream_t stream) {
    const float* x      = (const float*)d_in[0];
    const float* W_in   = (const float*)d_in[1];
    const float* conv_w = (const float*)d_in[2];
    const float* conv_b = (const float*)d_in[3];
    const float* W_x    = (const float*)d_in[4];
    const float* W_dt   = (const float*)d_in[5];
    const float* b_dt   = (const float*)d_in[6];
    const float* Dvec   = (const float*)d_in[7];
    const float* W_out  = (const float*)d_in[8];
    float* out = (float*)d_out;

    // Layout (u16 buffers: N_u16 elements occupy N_u16/2 floats). ~99 MB < 256 MiB.
    float* ws = (float*)d_ws;
    u16*   xiraw  = (u16*)ws;               //  0        .. 2097152  (2048*2048 u16)
    float* gate   = ws + 2097152;           //  2097152  .. 6291456  (4194304 f)
    u16*   xibf   = (u16*)(ws + 6291456);   //  6291456  .. 8388608  (2048*2048 u16)
    float* xdbl   = ws + 8388608;           //  8388608  .. 8585216  (196608 f)
    float* delta  = ws + 8585216;           //  8585216  .. 12779520 (4194304 f)
    float* localQ = ws + 12779520;          // 12779520  .. 16973824 (4194304 f)
    float* csum   = ws + 16973824;          // 16973824  .. 17235968 (262144 f)
    float* send   = ws + 17235968;          // 17235968  .. 17498112 (262144 f)
    u16*   xbf    = (u16*)(ws + 17498112);  // 17498112  .. 18546688 (2048*1024 u16)
    u16*   WinT   = (u16*)(ws + 18546688);  // 18546688  .. 20643840 (4096*1024 u16)
    u16*   WxT    = (u16*)(ws + 20643840);  // 20643840  .. 20742144 (96*2048 u16)
    u16*   WdtT   = (u16*)(ws + 20742144);  // 20742144  .. 20807680 (2048*64 u16)
    u16*   WoutT  = (u16*)(ws + 20807680);  // 20807680  .. 21856256 (1024*2048 u16)
    u16*   xdbf   = (u16*)(ws + 21856256);  // 21856256  .. 21921792 (2048*64 u16)
    float* Psk    = ws + 21921792;          // 21921792  .. 22708224 (786432 f)
    u16*   ybf    = (u16*)(ws + 22708224);  // 22708224  .. 24805376 (2048*2048 u16)

    // 1) fused prep: x->bf16 + all 4 weight transpose-casts
    prep_fused<<<3680, 256, 0, stream>>>(x, W_in, W_x, W_dt, W_out,
                                         xbf, WinT, WxT, WdtT, WoutT);
    // 2) x @ W_in -> split epilogue: xiraw (bf16) + gate = swish(res) (fp32)
    gemm_bf16<64, 2><<<dim3(4096 / 64, L_SEQ / 128), 256, 0, stream>>>(
        xbf, WinT, nullptr, nullptr, xiraw, gate, L_SEQ, 4096, DMODEL);
    // 3) xi = swish(causal_conv(xiraw)) -> bf16
    conv_swish<<<(L_SEQ * DIN) / 256, 256, 0, stream>>>(xiraw, conv_w, conv_b, xibf);
    // 4) xdbl = xi @ W_x  bf16 MFMA split-K x4 + reduce(+cast)
    gemm_bf16_sk<<<dim3(3, L_SEQ / 128, 4), 256, 0, stream>>>(
        xibf, DIN, WxT, DIN, Psk, L_SEQ, 96, DIN, 512);
    reduce_sk<<<(L_SEQ * 96) / 256, 256, 0, stream>>>(Psk, xdbl, xdbf);
    // 5) delta = softplus(xdbl[:, :64] @ W_dt + b_dt)
    gemm_bf16<64, 1><<<dim3(DIN / 64, L_SEQ / 128), 256, 0, stream>>>(
        xdbf, WdtT, delta, b_dt, nullptr, nullptr, L_SEQ, DIN, DTR);
    // 6) chunk-parallel scan (u = xibf bf16); scanC writes ybf directly
    scanA<<<dim3(DIN / 256, CCH), 256, 0, stream>>>(delta, xibf, xdbl, localQ, csum);
    scanB<<<(DIN * NST) / 256, 256, 0, stream>>>(localQ, csum, send);
    scanC<<<dim3(DIN / 256, CCH), 256, 0, stream>>>(delta, xibf, xdbl, localQ, send,
                                                    Dvec, gate, ybf);
    // 7) out = ygated @ W_out
    gemm_bf16<32, 0><<<dim3(DMODEL / 32, L_SEQ / 128), 256, 0, stream>>>(
        ybf, WoutT, out, nullptr, nullptr, nullptr, L_SEQ, DMODEL, DIN);
}